// Round 10
// baseline (106.994 us; speedup 1.0000x reference)
//
#include <hip/hip_runtime.h>
#include <hip/hip_bf16.h>
#include <stdint.h>

// B=4, S=1024, D=1024, N=32, R=128; T = B*S = 4096.
// Pipeline:
//   prep (one kernel): xb = bf16(x); FKT = bf16(fk)^T; RKT = bf16(rk)^T
//   ALLHW[t, n*128+r] = fw[t,n] * (xb @ FKT^T)   bf16  (GEMM1, 2-barrier 128^2)
//   h[t,r] = sum_n ALLHW[t, n*128+r]             bf16  (reduce)
//   out = sum_n diag(rw[:,n]) * (h @ rk[n])      f32   (gemm2_fused v3:
//         32x32x16 MFMA with FULL K=128 contraction (8 k-steps; r9 bug was 4),
//         h-frags direct global->reg, LDS 32KB, 3 blocks/CU)

typedef __attribute__((ext_vector_type(8))) short bf16x8;
typedef __attribute__((ext_vector_type(4))) float f32x4;
typedef __attribute__((ext_vector_type(16))) float f32x16;

#define GLOAD_LDS16(gp, lp) __builtin_amdgcn_global_load_lds( \
    (const __attribute__((address_space(1))) void*)(gp), \
    (__attribute__((address_space(3))) void*)(lp), 16, 0, 0)

__device__ __forceinline__ unsigned short f2bf(float f) {
  uint32_t u = __float_as_uint(f);
  u += 0x7FFFu + ((u >> 16) & 1u);   // RNE
  return (unsigned short)(u >> 16);
}
__device__ __forceinline__ float bf2f(unsigned short b) {
  return __uint_as_float(((uint32_t)b) << 16);
}

// ---------------- prep: cast x + transpose fk + transpose rk (merged) ----
__global__ void prep(const float* __restrict__ x,
                     const float* __restrict__ fk,
                     const float* __restrict__ rk,
                     unsigned short* __restrict__ xb,
                     unsigned short* __restrict__ fkt,
                     unsigned short* __restrict__ rkt) {
  __shared__ unsigned short tile[64][65];
  const int bid = blockIdx.x;
  const int tid = threadIdx.x;

  if (bid < 4096) {
    int i = bid * 256 + tid;
    float4 v = ((const float4*)x)[i];
    ushort4 o;
    o.x = f2bf(v.x); o.y = f2bf(v.y); o.z = f2bf(v.z); o.w = f2bf(v.w);
    ((ushort4*)xb)[i] = o;
    return;
  }

  const float* in;
  unsigned short* outp;
  int ROWS, COLS, tiles_per_batch, ctiles, tb;
  if (bid < 5120) {            // fk (32,1024,128) -> FKT (32,128,1024)
    in = fk; outp = fkt; ROWS = 1024; COLS = 128;
    tiles_per_batch = 32; ctiles = 2; tb = bid - 4096;
  } else {                     // rk (4096,1024) -> RKT (1024,4096)
    in = rk; outp = rkt; ROWS = 4096; COLS = 1024;
    tiles_per_batch = 1024; ctiles = 16; tb = bid - 5120;
  }
  int b  = tb / tiles_per_batch;
  int tt = tb % tiles_per_batch;
  int rt = tt / ctiles, ct = tt % ctiles;
  const float* inb = in + (size_t)b * ROWS * COLS;
  unsigned short* outb = outp + (size_t)b * ROWS * COLS;
  int lr = tid >> 6, lc = tid & 63;
  int r0 = rt * 64, c0 = ct * 64;
#pragma unroll
  for (int i = 0; i < 16; ++i) {
    int r = lr * 16 + i;
    tile[r][lc] = f2bf(inb[(size_t)(r0 + r) * COLS + c0 + lc]);
  }
  __syncthreads();
#pragma unroll
  for (int i = 0; i < 16; ++i) {
    int c = lr * 16 + i;
    outb[(size_t)(c0 + c) * ROWS + r0 + lc] = tile[lc][c];
  }
}

// ---------------- reduce: h[t,r] = sum_n ALLHW[t, n*128+r] ----------
__global__ void reduce_h(const unsigned short* __restrict__ allhw,
                         unsigned short* __restrict__ h) {
  int tid = threadIdx.x;
  int t = blockIdx.x * 16 + (tid >> 4);
  int r8 = tid & 15;
  const unsigned short* p = allhw + (size_t)t * 4096 + r8 * 8;
  float acc[8] = {0,0,0,0,0,0,0,0};
#pragma unroll
  for (int n = 0; n < 32; ++n) {
    bf16x8 v = *(const bf16x8*)(p + n * 128);
#pragma unroll
    for (int j = 0; j < 8; ++j) acc[j] += bf2f((unsigned short)v[j]);
  }
  bf16x8 o;
#pragma unroll
  for (int j = 0; j < 8; ++j) o[j] = (short)f2bf(acc[j]);
  *(bf16x8*)(h + (size_t)t * 128 + r8 * 8) = o;
}

// ---------------- GEMM1: C = fw-weighted (A @ BT^T), 2-barrier ------
__global__ __launch_bounds__(256, 2) void gemm_bt(
    const unsigned short* __restrict__ A,
    const unsigned short* __restrict__ BT,
    const float* __restrict__ fw,
    unsigned short* __restrict__ Cout) {
  constexpr int BM = 128, BN = 128, BK = 64;
  constexpr int K = 1024, N = 4096;
  constexpr int MREP = 4, NREP = 4;
  __shared__ __align__(16) unsigned short As[BM * BK];
  __shared__ __align__(16) unsigned short Bs[BN * BK];

  const int tid = threadIdx.x;
  const int lane = tid & 63, wid = tid >> 6;
  const int wy = wid >> 1, wx = wid & 1;
  const int brow = blockIdx.y * BM;
  const int bcol = blockIdx.x * BN;
  const int nexp = blockIdx.x;              // expert id (BN==128==R)

  f32x4 acc[MREP][NREP] = {};

  const int srow = tid >> 3;
  const int sslot = tid & 7;

  for (int k0 = 0; k0 < K; k0 += BK) {
#pragma unroll
    for (int i = 0; i < BM / 32; ++i) {
      int row = i * 32 + srow;
      int gslot = sslot ^ (row & 7);
      GLOAD_LDS16(A + (size_t)(brow + row) * K + k0 + gslot * 8,
                  &As[row * BK + sslot * 8]);
    }
#pragma unroll
    for (int i = 0; i < BN / 32; ++i) {
      int row = i * 32 + srow;
      int gslot = sslot ^ (row & 7);
      GLOAD_LDS16(BT + (size_t)(bcol + row) * K + k0 + gslot * 8,
                  &Bs[row * BK + sslot * 8]);
    }
    __syncthreads();

#pragma unroll
    for (int ks = 0; ks < 2; ++ks) {
      const int kg = lane >> 4;
      const int slot = ks * 4 + kg;
      bf16x8 af[MREP], bfr[NREP];
#pragma unroll
      for (int m = 0; m < MREP; ++m) {
        int row = wy * (BM / 2) + m * 16 + (lane & 15);
        af[m] = *(const bf16x8*)&As[row * BK + ((slot ^ (row & 7)) * 8)];
      }
#pragma unroll
      for (int n = 0; n < NREP; ++n) {
        int row = wx * (BN / 2) + n * 16 + (lane & 15);
        bfr[n] = *(const bf16x8*)&Bs[row * BK + ((slot ^ (row & 7)) * 8)];
      }
#pragma unroll
      for (int m = 0; m < MREP; ++m)
#pragma unroll
        for (int n = 0; n < NREP; ++n)
          acc[m][n] = __builtin_amdgcn_mfma_f32_16x16x32_bf16(
              af[m], bfr[n], acc[m][n], 0, 0, 0);
    }
    __syncthreads();
  }

  const int crow0 = brow + wy * (BM / 2);
  const int ccol0 = bcol + wx * (BN / 2);
#pragma unroll
  for (int m = 0; m < MREP; ++m) {
    int r0 = crow0 + m * 16 + ((lane >> 4) * 4);
    float fwv[4];
#pragma unroll
    for (int j = 0; j < 4; ++j) fwv[j] = fw[(size_t)(r0 + j) * 32 + nexp];
#pragma unroll
    for (int n = 0; n < NREP; ++n) {
      int c = ccol0 + n * 16 + (lane & 15);
#pragma unroll
      for (int j = 0; j < 4; ++j)
        Cout[(size_t)(r0 + j) * N + c] = f2bf(fwv[j] * acc[m][n][j]);
    }
  }
}

// ---------------- GEMM2 fused v3: 32x32x16 MFMA, full K=128 ----------
// h: (4096,128) bf16. rkt: (1024,4096) bf16 [d][n*128+r]. rw: (4096,32) f32.
// BM=256 (t), BN=32 (d). grid 512, XCD swizzle. 4 waves x 64-token strips.
// A-frags (h rows) direct global->reg: af[2][8] covers full r in [0,128).
// Per expert per wave: 8 ds_read_b128 + 16 mfma_32x32x16 + rw fold.
// LDS 32KB: Bs[2][32x128] dbuf + rw_lds 16KB; 3 blocks/CU (VGPR ~160).
__global__ __launch_bounds__(256, 3) void gemm2_fused(
    const unsigned short* __restrict__ h,
    const unsigned short* __restrict__ rkt,
    const float* __restrict__ rw,
    float* __restrict__ out) {
  constexpr int BM = 256, BN = 32;
  __shared__ __align__(16) unsigned short Bs[2][BN * 128];   // 2 x 8 KB
  __shared__ __align__(16) unsigned short rw_lds[32 * BM];   // 16 KB

  const int tid = threadIdx.x;
  const int lane = tid & 63, wid = tid >> 6;
  const int l31 = lane & 31;
  const int khalf = lane >> 5;
  // XCD swizzle: 512 wgs, chunk 64 per XCD (bijective)
  const int wg = blockIdx.x;
  const int swz = (wg & 7) * 64 + (wg >> 3);
  const int bcol = (swz >> 4) * BN;   // 32 d-col groups; 4 per XCD
  const int brow = (swz & 15) * BM;   // all 16 token tiles per XCD

  // ---- A-frags: h direct global->reg. af[mt][ks] = r in [ks*16+khalf*8, +8)
  // over ks in [0,8): covers the FULL r range [0,128).
  bf16x8 af[2][8];
#pragma unroll
  for (int mt = 0; mt < 2; ++mt) {
    const unsigned short* hp = h + (size_t)(brow + wid * 64 + mt * 32 + l31) * 128;
#pragma unroll
    for (int ks = 0; ks < 8; ++ks)
      af[mt][ks] = *(const bf16x8*)(hp + (ks * 2 + khalf) * 8);
  }

  // ---- stage rw transposed as bf16: rw_lds[n][t_local], thread=row ----
  {
    const float* rp = rw + (size_t)(brow + tid) * 32;
#pragma unroll
    for (int i = 0; i < 8; ++i) {
      float4 v = *(const float4*)(rp + i * 4);
      rw_lds[(i * 4 + 0) * BM + tid] = f2bf(v.x);
      rw_lds[(i * 4 + 1) * BM + tid] = f2bf(v.y);
      rw_lds[(i * 4 + 2) * BM + tid] = f2bf(v.z);
      rw_lds[(i * 4 + 3) * BM + tid] = f2bf(v.w);
    }
  }

  // B staging: 32 rows(d) x 16 slots = 512 slots, 2/thread; 16-slot XOR swz.
#define STG(nn, B) do { \
  _Pragma("unroll") for (int i_ = 0; i_ < 2; ++i_) { \
    int sid_ = tid + i_ * 256; \
    int row_ = sid_ >> 4, sl_ = sid_ & 15; \
    int gs_ = sl_ ^ (row_ & 15); \
    GLOAD_LDS16(rkt + (size_t)(bcol + row_) * 4096 + (nn) * 128 + gs_ * 8, \
                &(B)[row_ * 128 + sl_ * 8]); \
  } } while (0)

  f32x16 acc[2] = {};

  STG(0, Bs[0]);
  __syncthreads();   // rw_lds written + expert-0 tile landed

  for (int n = 0; n < 32; ++n) {
    const unsigned short* cur = Bs[n & 1];
    if (n < 31) STG(n + 1, Bs[(n + 1) & 1]);   // lands under MFMA below

    // B-frags: lane = col d (l31); slot = ks*2+khalf -> r = slot*8 in [0,128)
    bf16x8 bfr[8];
#pragma unroll
    for (int ks = 0; ks < 8; ++ks) {
      int slot = ks * 2 + khalf;
      bfr[ks] = *(const bf16x8*)&cur[l31 * 128 + ((slot ^ (l31 & 15)) * 8)];
    }

#pragma unroll
    for (int mt = 0; mt < 2; ++mt) {
      f32x16 accn = {};
#pragma unroll
      for (int ks = 0; ks < 8; ++ks)
        accn = __builtin_amdgcn_mfma_f32_32x32x16_bf16(af[mt][ks], bfr[ks],
                                                       accn, 0, 0, 0);
      // fold: acc += rw[t,n] * accn ; C/D row = (reg&3)+8*(reg>>2)+4*khalf
      const int rbase = wid * 64 + mt * 32 + 4 * khalf;
#pragma unroll
      for (int q = 0; q < 4; ++q) {
        ushort4 wv = *(const ushort4*)&rw_lds[n * BM + rbase + q * 8];
        acc[mt][q * 4 + 0] += bf2f(wv.x) * accn[q * 4 + 0];
        acc[mt][q * 4 + 1] += bf2f(wv.y) * accn[q * 4 + 1];
        acc[mt][q * 4 + 2] += bf2f(wv.z) * accn[q * 4 + 2];
        acc[mt][q * 4 + 3] += bf2f(wv.w) * accn[q * 4 + 3];
      }
    }
    __syncthreads();   // next tile staged + all waves done with cur
  }
#undef STG

  // ---- epilogue: f32 out; D col = l31, row = (reg&3)+8*(reg>>2)+4*khalf ----
#pragma unroll
  for (int mt = 0; mt < 2; ++mt) {
    const int rb = brow + wid * 64 + mt * 32 + 4 * khalf;
#pragma unroll
    for (int q = 0; q < 4; ++q)
#pragma unroll
      for (int j = 0; j < 4; ++j)
        out[(size_t)(rb + q * 8 + j) * 1024 + bcol + l31] = acc[mt][q * 4 + j];
  }
}

extern "C" void kernel_launch(void* const* d_in, const int* in_sizes, int n_in,
                              void* d_out, int out_size, void* d_ws, size_t ws_size,
                              hipStream_t stream) {
  const float* x  = (const float*)d_in[0];
  const float* fw = (const float*)d_in[1];
  const float* rw = (const float*)d_in[2];
  const float* fk = (const float*)d_in[3];
  const float* rk = (const float*)d_in[4];
  float* out = (float*)d_out;

  char* ws = (char*)d_ws;
  unsigned short* xb    = (unsigned short*)(ws);                // 8 MB (4096x1024)
  unsigned short* fkt   = (unsigned short*)(ws + (8u  << 20));  // 8 MB; reused as h after GEMM1
  unsigned short* rkt   = (unsigned short*)(ws + (16u << 20));  // 8 MB (1024x4096)
  unsigned short* allhw = (unsigned short*)(ws + (24u << 20));  // 32 MB (4096x4096)
  unsigned short* hbuf  = fkt;                                  // (4096x128) bf16

  prep<<<6144, 256, 0, stream>>>(x, fk, rk, xb, fkt, rkt);
  gemm_bt<<<dim3(32, 32), 256, 0, stream>>>(xb, fkt, fw, allhw);
  reduce_h<<<256, 256, 0, stream>>>(allhw, hbuf);
  gemm2_fused<<<512, 256, 0, stream>>>(hbuf, rkt, rw, out);
}

// Round 11
// 93.833 us; speedup vs baseline: 1.1403x; 1.1403x over previous
//
#include <hip/hip_runtime.h>
#include <hip/hip_bf16.h>
#include <stdint.h>

// B=4, S=1024, D=1024, N=32, R=128; T = B*S = 4096.
// Best-measured assembly (rounds 1-10 ledger):
//   prep   (r8 merged, ~8us): xb = bf16(x); FKT = bf16(fk)^T; RKT = bf16(rk)^T
//   gemm_bt(r6/r8 2D-grid 128^2 2-barrier, 40.3us / 853 TF = m97-ceiling @K=1024)
//   reduce (r2 form, ~5us)
//   gemm2  (r7 form, ~35us / ~980 TF eff): BM=256/BN=32, h->LDS->regs hoist,
//          pool reused as Bs dbuf, XCD swizzle, 2 blocks/CU.
// Regressions measured and reverted: 8-phase gemm1 (688 TF), vmcnt ring (46us),
// 4-expert groups (46us), 32x32 MFMA (51us, VGPR-spill), gemm1 XCD swz (+14MB).

typedef __attribute__((ext_vector_type(8))) short bf16x8;
typedef __attribute__((ext_vector_type(4))) float f32x4;

#define GLOAD_LDS16(gp, lp) __builtin_amdgcn_global_load_lds( \
    (const __attribute__((address_space(1))) void*)(gp), \
    (__attribute__((address_space(3))) void*)(lp), 16, 0, 0)

__device__ __forceinline__ unsigned short f2bf(float f) {
  uint32_t u = __float_as_uint(f);
  u += 0x7FFFu + ((u >> 16) & 1u);   // RNE
  return (unsigned short)(u >> 16);
}
__device__ __forceinline__ float bf2f(unsigned short b) {
  return __uint_as_float(((uint32_t)b) << 16);
}

// ---------------- prep: cast x + transpose fk + transpose rk (merged) ----
__global__ void prep(const float* __restrict__ x,
                     const float* __restrict__ fk,
                     const float* __restrict__ rk,
                     unsigned short* __restrict__ xb,
                     unsigned short* __restrict__ fkt,
                     unsigned short* __restrict__ rkt) {
  __shared__ unsigned short tile[64][65];
  const int bid = blockIdx.x;
  const int tid = threadIdx.x;

  if (bid < 4096) {
    int i = bid * 256 + tid;
    float4 v = ((const float4*)x)[i];
    ushort4 o;
    o.x = f2bf(v.x); o.y = f2bf(v.y); o.z = f2bf(v.z); o.w = f2bf(v.w);
    ((ushort4*)xb)[i] = o;
    return;
  }

  const float* in;
  unsigned short* outp;
  int ROWS, COLS, tiles_per_batch, ctiles, tb;
  if (bid < 5120) {            // fk (32,1024,128) -> FKT (32,128,1024)
    in = fk; outp = fkt; ROWS = 1024; COLS = 128;
    tiles_per_batch = 32; ctiles = 2; tb = bid - 4096;
  } else {                     // rk (4096,1024) -> RKT (1024,4096)
    in = rk; outp = rkt; ROWS = 4096; COLS = 1024;
    tiles_per_batch = 1024; ctiles = 16; tb = bid - 5120;
  }
  int b  = tb / tiles_per_batch;
  int tt = tb % tiles_per_batch;
  int rt = tt / ctiles, ct = tt % ctiles;
  const float* inb = in + (size_t)b * ROWS * COLS;
  unsigned short* outb = outp + (size_t)b * ROWS * COLS;
  int lr = tid >> 6, lc = tid & 63;
  int r0 = rt * 64, c0 = ct * 64;
#pragma unroll
  for (int i = 0; i < 16; ++i) {
    int r = lr * 16 + i;
    tile[r][lc] = f2bf(inb[(size_t)(r0 + r) * COLS + c0 + lc]);
  }
  __syncthreads();
#pragma unroll
  for (int i = 0; i < 16; ++i) {
    int c = lr * 16 + i;
    outb[(size_t)(c0 + c) * ROWS + r0 + lc] = tile[lc][c];
  }
}

// ---------------- reduce: h[t,r] = sum_n ALLHW[t, n*128+r] ----------
__global__ void reduce_h(const unsigned short* __restrict__ allhw,
                         unsigned short* __restrict__ h) {
  int tid = threadIdx.x;
  int t = blockIdx.x * 16 + (tid >> 4);
  int r8 = tid & 15;
  const unsigned short* p = allhw + (size_t)t * 4096 + r8 * 8;
  float acc[8] = {0,0,0,0,0,0,0,0};
#pragma unroll
  for (int n = 0; n < 32; ++n) {
    bf16x8 v = *(const bf16x8*)(p + n * 128);
#pragma unroll
    for (int j = 0; j < 8; ++j) acc[j] += bf2f((unsigned short)v[j]);
  }
  bf16x8 o;
#pragma unroll
  for (int j = 0; j < 8; ++j) o[j] = (short)f2bf(acc[j]);
  *(bf16x8*)(h + (size_t)t * 128 + r8 * 8) = o;
}

// ---------------- GEMM1: C = fw-weighted (A @ BT^T), 2-barrier ------
__global__ __launch_bounds__(256, 2) void gemm_bt(
    const unsigned short* __restrict__ A,
    const unsigned short* __restrict__ BT,
    const float* __restrict__ fw,
    unsigned short* __restrict__ Cout) {
  constexpr int BM = 128, BN = 128, BK = 64;
  constexpr int K = 1024, N = 4096;
  constexpr int MREP = 4, NREP = 4;
  __shared__ __align__(16) unsigned short As[BM * BK];
  __shared__ __align__(16) unsigned short Bs[BN * BK];

  const int tid = threadIdx.x;
  const int lane = tid & 63, wid = tid >> 6;
  const int wy = wid >> 1, wx = wid & 1;
  const int brow = blockIdx.y * BM;
  const int bcol = blockIdx.x * BN;
  const int nexp = blockIdx.x;              // expert id (BN==128==R)

  f32x4 acc[MREP][NREP] = {};

  const int srow = tid >> 3;
  const int sslot = tid & 7;

  for (int k0 = 0; k0 < K; k0 += BK) {
#pragma unroll
    for (int i = 0; i < BM / 32; ++i) {
      int row = i * 32 + srow;
      int gslot = sslot ^ (row & 7);
      GLOAD_LDS16(A + (size_t)(brow + row) * K + k0 + gslot * 8,
                  &As[row * BK + sslot * 8]);
    }
#pragma unroll
    for (int i = 0; i < BN / 32; ++i) {
      int row = i * 32 + srow;
      int gslot = sslot ^ (row & 7);
      GLOAD_LDS16(BT + (size_t)(bcol + row) * K + k0 + gslot * 8,
                  &Bs[row * BK + sslot * 8]);
    }
    __syncthreads();

#pragma unroll
    for (int ks = 0; ks < 2; ++ks) {
      const int kg = lane >> 4;
      const int slot = ks * 4 + kg;
      bf16x8 af[MREP], bfr[NREP];
#pragma unroll
      for (int m = 0; m < MREP; ++m) {
        int row = wy * (BM / 2) + m * 16 + (lane & 15);
        af[m] = *(const bf16x8*)&As[row * BK + ((slot ^ (row & 7)) * 8)];
      }
#pragma unroll
      for (int n = 0; n < NREP; ++n) {
        int row = wx * (BN / 2) + n * 16 + (lane & 15);
        bfr[n] = *(const bf16x8*)&Bs[row * BK + ((slot ^ (row & 7)) * 8)];
      }
#pragma unroll
      for (int m = 0; m < MREP; ++m)
#pragma unroll
        for (int n = 0; n < NREP; ++n)
          acc[m][n] = __builtin_amdgcn_mfma_f32_16x16x32_bf16(
              af[m], bfr[n], acc[m][n], 0, 0, 0);
    }
    __syncthreads();
  }

  const int crow0 = brow + wy * (BM / 2);
  const int ccol0 = bcol + wx * (BN / 2);
#pragma unroll
  for (int m = 0; m < MREP; ++m) {
    int r0 = crow0 + m * 16 + ((lane >> 4) * 4);
    float fwv[4];
#pragma unroll
    for (int j = 0; j < 4; ++j) fwv[j] = fw[(size_t)(r0 + j) * 32 + nexp];
#pragma unroll
    for (int n = 0; n < NREP; ++n) {
      int c = ccol0 + n * 16 + (lane & 15);
#pragma unroll
      for (int j = 0; j < 4; ++j)
        Cout[(size_t)(r0 + j) * N + c] = f2bf(fwv[j] * acc[m][n][j]);
    }
  }
}

// ---------------- GEMM2 fused (r7 form): out = sum_n diag(rw_n)*(h @ rk[n]) --
// h: (4096,128) bf16. rkt: (1024,4096) bf16 [d][n*128+r]. rw: (4096,32) f32.
// BM=256 (t), BN=32 (d). 1D grid 512, XCD swizzle (rkt slice L2-resident).
// LDS 80KB: pool 64KB holds h during af hoist, then 2x8KB Bs dbuf; rw 16KB.
__global__ __launch_bounds__(256, 2) void gemm2_fused(
    const unsigned short* __restrict__ h,
    const unsigned short* __restrict__ rkt,
    const float* __restrict__ rw,
    float* __restrict__ out) {
  constexpr int BM = 256, BN = 32;
  __shared__ __align__(16) unsigned short pool[BM * 128];      // 64 KB
  __shared__ __align__(16) unsigned short rw_lds[32 * BM];     // 16 KB

  const int tid = threadIdx.x;
  const int lane = tid & 63, wid = tid >> 6;   // wave owns 64-token strip
  // XCD swizzle: 512 wgs, chunk 64 per XCD (bijective)
  const int wg = blockIdx.x;
  const int swz = (wg & 7) * 64 + (wg >> 3);
  const int bcol = (swz >> 4) * BN;   // 32 d-col groups; 4 per XCD
  const int brow = (swz & 15) * BM;   // all 16 token tiles per XCD

  // ---- stage h block (once): 256 x 128, swizzled source ----
  {
    int srow = tid >> 4, sslot = tid & 15;
#pragma unroll
    for (int i = 0; i < 16; ++i) {
      int row = i * 16 + srow;
      int gs = sslot ^ (row & 7);
      GLOAD_LDS16(h + (size_t)(brow + row) * 128 + gs * 8,
                  &pool[row * 128 + sslot * 8]);
    }
  }
  // ---- stage rw transposed as bf16: rw_lds[n][t_local], thread=row ----
  {
    const float* rp = rw + (size_t)(brow + tid) * 32;
#pragma unroll
    for (int i = 0; i < 8; ++i) {
      float4 v = *(const float4*)(rp + i * 4);
      rw_lds[(i * 4 + 0) * BM + tid] = f2bf(v.x);
      rw_lds[(i * 4 + 1) * BM + tid] = f2bf(v.y);
      rw_lds[(i * 4 + 2) * BM + tid] = f2bf(v.z);
      rw_lds[(i * 4 + 3) * BM + tid] = f2bf(v.w);
    }
  }
  __syncthreads();

  // ---- hoist A-frags to regs (h LDS about to be overwritten) ----
  const int kg = lane >> 4;
  const int lrow = lane & 15;
  bf16x8 af[4][4];
#pragma unroll
  for (int m = 0; m < 4; ++m) {
    int row = wid * 64 + m * 16 + lrow;
#pragma unroll
    for (int s = 0; s < 4; ++s) {
      int slot = s * 4 + kg;
      af[m][s] = *(const bf16x8*)&pool[row * 128 + ((slot ^ (row & 7)) * 8)];
    }
  }
  __syncthreads();   // all waves' ds_reads done before pool reuse

  unsigned short* Bs0 = pool;               // 8 KB (32 x 128)
  unsigned short* Bs1 = pool + 32 * 128;    // next 8 KB

  // B-tile staging: 32 rows x 128 cols = 512 16B-slots, 2 per thread
#define STG(nn, B) do { \
  _Pragma("unroll") for (int i_ = 0; i_ < 2; ++i_) { \
    int sid_ = tid + i_ * 256; \
    int row_ = sid_ >> 4, sl_ = sid_ & 15; \
    int gs_ = sl_ ^ (row_ & 7); \
    GLOAD_LDS16(rkt + (size_t)(bcol + row_) * 4096 + (nn) * 128 + gs_ * 8, \
                &(B)[row_ * 128 + sl_ * 8]); \
  } } while (0)

  f32x4 acc[4][2] = {};

  STG(0, Bs0);
  __syncthreads();   // expert-0 tile landed

  for (int n = 0; n < 32; ++n) {
    const unsigned short* cur = (n & 1) ? Bs1 : Bs0;
    unsigned short* nxt = (n & 1) ? Bs0 : Bs1;
    if (n < 31) STG(n + 1, nxt);   // lands during the MFMA below

    f32x4 accn[4][2] = {};
#pragma unroll
    for (int s = 0; s < 4; ++s) {
      int slot = s * 4 + kg;
      bf16x8 bfr[2];
#pragma unroll
      for (int j = 0; j < 2; ++j) {
        int drow = j * 16 + lrow;
        bfr[j] = *(const bf16x8*)&cur[drow * 128 + ((slot ^ (drow & 7)) * 8)];
      }
#pragma unroll
      for (int m = 0; m < 4; ++m)
#pragma unroll
        for (int j = 0; j < 2; ++j)
          accn[m][j] = __builtin_amdgcn_mfma_f32_16x16x32_bf16(
              af[m][s], bfr[j], accn[m][j], 0, 0, 0);
    }

    // fold: acc += rw[t,n] * accn
#pragma unroll
    for (int m = 0; m < 4; ++m) {
      int r0 = wid * 64 + m * 16 + (lane >> 4) * 4;
      ushort4 wv4 = *(const ushort4*)&rw_lds[n * BM + r0];
      float w0 = bf2f(wv4.x), w1 = bf2f(wv4.y), w2 = bf2f(wv4.z), w3 = bf2f(wv4.w);
#pragma unroll
      for (int j = 0; j < 2; ++j) {
        acc[m][j][0] += w0 * accn[m][j][0];
        acc[m][j][1] += w1 * accn[m][j][1];
        acc[m][j][2] += w2 * accn[m][j][2];
        acc[m][j][3] += w3 * accn[m][j][3];
      }
    }
    __syncthreads();   // next tile staged + all waves done with cur
  }
#undef STG

  // ---- epilogue: f32 out ----
#pragma unroll
  for (int m = 0; m < 4; ++m) {
    int r0 = brow + wid * 64 + m * 16 + ((lane >> 4) * 4);
#pragma unroll
    for (int j = 0; j < 2; ++j) {
      int c = bcol + j * 16 + lrow;
#pragma unroll
      for (int q = 0; q < 4; ++q)
        out[(size_t)(r0 + q) * 1024 + c] = acc[m][j][q];
    }
  }
}

extern "C" void kernel_launch(void* const* d_in, const int* in_sizes, int n_in,
                              void* d_out, int out_size, void* d_ws, size_t ws_size,
                              hipStream_t stream) {
  const float* x  = (const float*)d_in[0];
  const float* fw = (const float*)d_in[1];
  const float* rw = (const float*)d_in[2];
  const float* fk = (const float*)d_in[3];
  const float* rk = (const float*)d_in[4];
  float* out = (float*)d_out;

  char* ws = (char*)d_ws;
  unsigned short* xb    = (unsigned short*)(ws);                // 8 MB (4096x1024)
  unsigned short* fkt   = (unsigned short*)(ws + (8u  << 20));  // 8 MB; reused as h after GEMM1
  unsigned short* rkt   = (unsigned short*)(ws + (16u << 20));  // 8 MB (1024x4096)
  unsigned short* allhw = (unsigned short*)(ws + (24u << 20));  // 32 MB (4096x4096)
  unsigned short* hbuf  = fkt;                                  // (4096x128) bf16

  prep<<<6144, 256, 0, stream>>>(x, fk, rk, xb, fkt, rkt);
  gemm_bt<<<dim3(32, 32), 256, 0, stream>>>(xb, fkt, fw, allhw);
  reduce_h<<<256, 256, 0, stream>>>(allhw, hbuf);
  gemm2_fused<<<512, 256, 0, stream>>>(hbuf, rkt, rw, out);
}